// Round 5
// baseline (16.024 us; speedup 1.0000x reference)
//
#include <hip/hip_runtime.h>
#include <math.h>

#define DIM 4096
#define BATCH 8192
#define NCHUNK 16            // prefix-table chunks
#define CHUNK 256            // j per chunk (== K1 block size)
#define K2_BLOCKS 32
#define K2_NT 256

// d_ws layout (bytes); d_ws is ~268 MB, we use ~66 KB
#define TABLE_OFF  0                       // float4[DIM]   within-chunk inclusive prefixes
#define CHUNK_OFF  (DIM * 16)              // float4[NCHUNK] chunk totals
#define ACC_OFF    (CHUNK_OFF + 256)       // float[4] global accumulators
#define TICKET_OFF (ACC_OFF + 16)          // unsigned int block-completion ticket

// K1: per-chunk inclusive prefix of the 4 series
//   {g, g*log(j+1), g*log(lam), g*log(1-lam)}  -> d_ws table, chunk totals.
// Block 0 also zeroes the K2 accumulators + ticket (stream order makes this safe).
__global__ __launch_bounds__(CHUNK)
void k1_table(const float* __restrict__ lambdas,
              const float* __restrict__ gammas,
              float4* __restrict__ table,
              float4* __restrict__ chunktot,
              float* __restrict__ accs,
              unsigned int* __restrict__ ticket)
{
    __shared__ float4 wv[CHUNK / 64];
    const int t = threadIdx.x;
    const int b = blockIdx.x;
    const int j = b * CHUNK + t;
    const int lane = t & 63;
    const int wave = t >> 6;

    float g = gammas[j];
    float l = lambdas[j];
    float v0 = g;
    float v1 = g * __logf((float)(j + 1));
    float v2 = g * __logf(l);
    float v3 = g * __logf(1.0f - l);      // lam in (0.05,0.95): log1p safe as log

    // wave-level inclusive scan (width 64)
    float i0 = v0, i1 = v1, i2 = v2, i3 = v3;
    #pragma unroll
    for (int off = 1; off < 64; off <<= 1) {
        float y0 = __shfl_up(i0, off, 64);
        float y1 = __shfl_up(i1, off, 64);
        float y2 = __shfl_up(i2, off, 64);
        float y3 = __shfl_up(i3, off, 64);
        if (lane >= off) { i0 += y0; i1 += y1; i2 += y2; i3 += y3; }
    }
    if (lane == 63) wv[wave] = make_float4(i0, i1, i2, i3);

    if (b == 0) {                          // zero K2 state (visible at K1 end)
        if (t < 4) accs[t] = 0.0f;
        if (t == 4) *ticket = 0u;
    }
    __syncthreads();

    // add preceding wave totals -> chunk-inclusive prefix
    #pragma unroll
    for (int w = 0; w < CHUNK / 64; ++w) {
        if (w < wave) {
            float4 o = wv[w];
            i0 += o.x; i1 += o.y; i2 += o.z; i3 += o.w;
        }
    }
    table[j] = make_float4(i0, i1, i2, i3);
    if (t == CHUNK - 1) chunktot[b] = make_float4(i0, i1, i2, i3);
}

// K2: one beta per thread. K via the reference's exact IEEE f32 op sequence,
// join against the prefix table, block reduce, global float atomics, and the
// last block (ticket) runs the scalar epilogue.
__global__ __launch_bounds__(K2_NT)
void k2_join(const float* __restrict__ betas,
             const float4* __restrict__ table,
             const float4* __restrict__ chunktot,
             float* __restrict__ accs,
             unsigned int* __restrict__ ticket,
             float* __restrict__ out)
{
    __shared__ float4 raw[NCHUNK];
    __shared__ float4 red[K2_NT / 64];
    const int t = threadIdx.x;
    const int lane = t & 63;
    const int wave = t >> 6;
    const int tid = blockIdx.x * K2_NT + t;

    if (t < NCHUNK) raw[t] = chunktot[t];

    float beta = betas[tid];
    float lamb = 1.0f - 1.0f / beta;            // IEEE divides: floor fidelity
    float kf   = 1.0f / (1.0f - lamb) - 1.0f;
    int K = (int)floorf(kf);
    K = min(max(K, 1), DIM - 1);
    float lk = __logf((float)K);
    __syncthreads();

    // chunk-exclusive base + within-chunk prefix at K-1  == sum_{j<K}
    const int c = (K - 1) >> 8;
    float b0 = 0.f, b1 = 0.f, b2 = 0.f, b3 = 0.f;
    for (int w = 0; w < c; ++w) {
        float4 o = raw[w];
        b0 += o.x; b1 += o.y; b2 += o.z; b3 += o.w;
    }
    float4 p = table[K - 1];
    float G  = b0 + p.x;
    float a0 = lk * G - (b1 + p.y);             // ixt contribution
    float a1 = G;                               // n_I
    float a2 = b2 + p.z;                        // S_lambda
    float a3 = b3 + p.w;                        // S_lambda_comp

    #pragma unroll
    for (int off = 32; off > 0; off >>= 1) {
        a0 += __shfl_down(a0, off, 64);
        a1 += __shfl_down(a1, off, 64);
        a2 += __shfl_down(a2, off, 64);
        a3 += __shfl_down(a3, off, 64);
    }
    if (lane == 0) red[wave] = make_float4(a0, a1, a2, a3);
    __syncthreads();

    if (t == 0) {
        float s0 = 0.f, s1 = 0.f, s2 = 0.f, s3 = 0.f;
        #pragma unroll
        for (int w = 0; w < K2_NT / 64; ++w) {
            float4 rv = red[w];
            s0 += rv.x; s1 += rv.y; s2 += rv.z; s3 += rv.w;
        }
        atomicAdd(&accs[0], s0);
        atomicAdd(&accs[1], s1);
        atomicAdd(&accs[2], s2);
        atomicAdd(&accs[3], s3);
        __threadfence();
        unsigned int old = atomicAdd(ticket, 1u);
        if (old == K2_BLOCKS - 1) {
            // all other blocks' adds are visible (fence + device-scope RMW)
            float ixt = atomicAdd(&accs[0], 0.0f);
            float nI  = atomicAdd(&accs[1], 0.0f);
            float Sl  = atomicAdd(&accs[2], 0.0f);
            float Sl1 = atomicAdd(&accs[3], 0.0f);
            float inv_nI = 1.0f / nI;
            float gm_term  = __expf(Sl  * inv_nI);
            float gm_comp  = __expf(Sl1 * inv_nI);
            float exp_term = __expf(2.0f * ixt * inv_nI);
            float log_term = -nI * 0.5f * __logf(gm_comp + exp_term * gm_term);
            float rhs = 1.0f - (ixt + log_term);   // IXY = 1
            float l1  = 1.0f - ixt * 0.1f;         // HX = 10
            if (l1 < 0.0f) l1 = fabsf(l1) * 20.0f;
            out[0] = rhs;
            out[1] = l1 * l1;                      // C=1, ALPHA=2
        }
    }
}

extern "C" void kernel_launch(void* const* d_in, const int* in_sizes, int n_in,
                              void* d_out, int out_size, void* d_ws, size_t ws_size,
                              hipStream_t stream) {
    const float* betas   = (const float*)d_in[0];
    const float* lambdas = (const float*)d_in[1];
    const float* gammas  = (const float*)d_in[2];
    char* ws = (char*)d_ws;
    float4* table          = (float4*)(ws + TABLE_OFF);
    float4* chunktot       = (float4*)(ws + CHUNK_OFF);
    float* accs            = (float*)(ws + ACC_OFF);
    unsigned int* ticket   = (unsigned int*)(ws + TICKET_OFF);

    k1_table<<<NCHUNK, CHUNK, 0, stream>>>(lambdas, gammas, table, chunktot, accs, ticket);
    k2_join<<<K2_BLOCKS, K2_NT, 0, stream>>>(betas, table, chunktot, accs, ticket,
                                             (float*)d_out);
}